// Round 10
// baseline (47.749 us; speedup 1.0000x reference)
//
#include <hip/hip_runtime.h>
#include <hip/hip_bf16.h>

// ToneMappingCurveLoss, phase-split variant.
// K1: input -> binmap (8b/pixel) + per-block counts.  (3 linear streams)
// K2: per-channel dsum_c[bin] += w_c*(pred_c - targ_c). (3 linear streams)
// stage2: f64 reduce of [64][rows] partials -> scalar.
// Rationale: steady state is half-L3-evicted (harness re-poisons 268MB d_ws
// between replays); single-kernel 9-stream version is stuck at ~40us
// (3.8 TB/s). Fewer concurrent streams + longer contiguous runs per block
// tests the DRAM/stream-inefficiency hypothesis.

#define CH4 65536         // HW/4 (float4 groups per channel plane)
#define NBINS 16
#define NCOLS 64          // 16 counts + 3*16 per-channel dsums

typedef float f4 __attribute__((ext_vector_type(4)));

__device__ __forceinline__ float luma_exact(float r, float g, float b) {
    // match numpy/jax f32 evaluation order, no FMA contraction
    return __fadd_rn(__fadd_rn(__fmul_rn(0.299f, r), __fmul_rn(0.587f, g)),
                     __fmul_rn(0.114f, b));
}

// ---- K1: bins + counts. Block owns contiguous 512-group tile. ----
__global__ __launch_bounds__(256) void k1_bins(
    const f4* __restrict__ input, unsigned* __restrict__ binmap,
    float* __restrict__ partials, int G, int rows)
{
    __shared__ unsigned long long cl[256], ch[256];
    const int t = threadIdx.x;
    unsigned long long cLo = 0ULL, cHi = 0ULL;   // 8b per bin, <=8 incs here

    const int stride = gridDim.x * 512;
    for (long long base = (long long)blockIdx.x * 512; base < G; base += stride) {
        #pragma unroll
        for (int half = 0; half < 2; ++half) {
            const int g = (int)base + half * 256 + t;
            if (g < G) {
                const int a = (g >> 16) * (3 * CH4) + (g & (CH4 - 1));
                const f4 i0 = input[a];
                const f4 i1 = input[a + CH4];
                const f4 i2 = input[a + 2 * CH4];
                unsigned code = 0u;
                #pragma unroll
                for (int j = 0; j < 4; ++j) {
                    const float il = luma_exact(i0[j], i1[j], i2[j]);
                    int b = (int)floorf(__fmul_rn(il, 16.0f));
                    b = min(max(b, 0), NBINS - 1);
                    if (il >= 1.0f) b = 16;       // excluded sentinel
                    code |= (unsigned)b << (8 * j);
                    if (b < 16) {
                        const unsigned long long inc = 1ULL << ((b & 7) * 8);
                        if (b < 8) cLo += inc; else cHi += inc;
                    }
                }
                binmap[g] = code;
            }
        }
    }

    cl[t] = cLo; ch[t] = cHi;
    __syncthreads();
    const int b = t >> 4, l = t & 15;
    int c = 0;
    #pragma unroll
    for (int k = 0; k < 16; ++k) {
        const unsigned long long p = (b < 8) ? cl[k * 16 + l] : ch[k * 16 + l];
        c += (int)((p >> ((b & 7) * 8)) & 0xFFULL);
    }
    #pragma unroll
    for (int k = 8; k; k >>= 1) c += __shfl_down(c, k, 16);
    if (l == 0) partials[b * rows + blockIdx.x] = (float)c;   // cols 0..15
}

// ---- K2: per-channel weighted dsum. grid = 3 * blocksPerChan. ----
__global__ __launch_bounds__(256) void k2_acc(
    const f4* __restrict__ pred, const f4* __restrict__ target,
    const unsigned* __restrict__ binmap, float* __restrict__ partials,
    int G, int rows, int blocksPerChan)
{
    __shared__ float dsh[NBINS * 256];      // 16 KB, per-thread slots
    const int t = threadIdx.x;
    const int ch_ = blockIdx.x % 3;
    const int blk = blockIdx.x / 3;
    const float w = (ch_ == 0) ? 0.299f : ((ch_ == 1) ? 0.587f : 0.114f);
    const int cOff = ch_ * CH4;

    #pragma unroll
    for (int k = 0; k < NBINS; ++k) dsh[k * 256 + t] = 0.0f;
    __syncthreads();

    const int stride = blocksPerChan * 512;
    for (long long base = (long long)blk * 512; base < G; base += stride) {
        #pragma unroll
        for (int half = 0; half < 2; ++half) {
            const int g = (int)base + half * 256 + t;
            if (g < G) {
                const int a = (g >> 16) * (3 * CH4) + cOff + (g & (CH4 - 1));
                const f4 p  = __builtin_nontemporal_load(&pred[a]);
                const f4 tv = __builtin_nontemporal_load(&target[a]);
                const unsigned bm = binmap[g];
                #pragma unroll
                for (int j = 0; j < 4; ++j) {
                    const int b = (int)((bm >> (8 * j)) & 0xFFu);
                    if (b < 16)
                        dsh[b * 256 + t] +=
                            __fmul_rn(w, p[j]) - __fmul_rn(w, tv[j]);
                }
            }
        }
    }

    __syncthreads();
    const int b = t >> 4, l = t & 15;
    float s = 0.0f;
    #pragma unroll
    for (int k = 0; k < 16; ++k) s += dsh[b * 256 + k * 16 + l];
    #pragma unroll
    for (int k = 8; k; k >>= 1) s += __shfl_down(s, k, 16);
    if (l == 0)
        partials[(NBINS + ch_ * NBINS + b) * rows + blk] = s; // cols 16..63
}

__global__ __launch_bounds__(1024) void tm_stage2(
    const float4* __restrict__ partials4,  // column-major [NCOLS][rows/4]
    float* __restrict__ out, int rows4)
{
    __shared__ double col[NCOLS];
    const int t = threadIdx.x;          // 1024 = 64 cols x 16 threads
    const int c = t >> 4;
    const int l = t & 15;

    double s = 0.0;
    for (int k = l; k < rows4; k += 16) {
        const float4 v = partials4[c * rows4 + k];
        s += (double)v.x + (double)v.y + (double)v.z + (double)v.w;
    }
    #pragma unroll
    for (int k = 8; k; k >>= 1) s += __shfl_down(s, k, 16);
    if (l == 0) col[c] = s;
    __syncthreads();

    if (t == 0) {
        double acc = 0.0;
        #pragma unroll
        for (int i = 0; i < NBINS; ++i) {
            const double cnt = col[i];
            if (cnt > 0.0) {
                const double ds = col[NBINS + i] + col[2 * NBINS + i]
                                + col[3 * NBINS + i];
                acc += fabs(ds) / cnt;
            }
        }
        out[0] = (float)(acc / (double)NBINS);
    }
}

extern "C" void kernel_launch(void* const* d_in, const int* in_sizes, int n_in,
                              void* d_out, int out_size, void* d_ws, size_t ws_size,
                              hipStream_t stream) {
    const float* pred   = (const float*)d_in[0];
    const float* target = (const float*)d_in[1];
    const float* input  = (const float*)d_in[2];

    const int G = in_sizes[0] / 12;    // pixel float4-groups (1048576 here)

    const int blocksPerChan = 2048;    // 512-group contiguous tile per block
    const int rows = blocksPerChan;    // multiple of 4
    float* partials = (float*)d_ws;                       // [64][rows] f32
    unsigned* binmap = (unsigned*)(partials + (size_t)NCOLS * rows); // [G] u32

    k1_bins<<<blocksPerChan, 256, 0, stream>>>(
        (const f4*)input, binmap, partials, G, rows);
    k2_acc<<<3 * blocksPerChan, 256, 0, stream>>>(
        (const f4*)pred, (const f4*)target, binmap, partials,
        G, rows, blocksPerChan);
    tm_stage2<<<1, 1024, 0, stream>>>(
        (const float4*)partials, (float*)d_out, rows / 4);
}

// Round 11
// 42.299 us; speedup vs baseline: 1.1288x; 1.1288x over previous
//
#include <hip/hip_runtime.h>
#include <hip/hip_bf16.h>

// ToneMappingCurveLoss: luma-binned mean-difference loss.
// Inputs: pred, target, input_img: [16, 3, 512, 512] f32. Output: 1 f32 scalar.
// |psum/c - tsum/c| == |sum(pl-tl)|/c -> per bin accumulate only count and
// dsum. Hot loop (identical to R8): nontemporal 16B loads, 3 phases
// (input->bins, pred->pl, target->accumulate), per-THREAD LDS slot
// dsh[bin][tid] (no atomics, conflict-free), byte-packed counts in two u64
// registers. R11 change: counts reduced IN REGISTERS (SWAR 16b expand +
// u64 shuffle tree) instead of 4KB LDS arrays -> LDS 20.5KB -> 16.6KB ->
// 9 blocks/CU capacity -> all 2048 blocks co-resident (kills the
// 256-block straggler tail of the 7-blocks/CU config).

#define CH4 65536         // HW/4 (float4 groups per channel)
#define NBINS 16
#define NCOL 32           // partial columns: 16 counts + 16 dsums

typedef float f4 __attribute__((ext_vector_type(4)));

__device__ __forceinline__ float luma_exact(float r, float g, float b) {
    // match numpy/jax f32 evaluation order, no FMA contraction
    return __fadd_rn(__fadd_rn(__fmul_rn(0.299f, r), __fmul_rn(0.587f, g)),
                     __fmul_rn(0.114f, b));
}

__global__ __launch_bounds__(256) void tm_stage1(
    const f4* __restrict__ pred, const f4* __restrict__ target,
    const f4* __restrict__ input,
    float* __restrict__ partials,   // column-major [NCOL][rows]
    int G, int rows)
{
    __shared__ float dsh[NBINS * 256];       // 16 KB: [bin][tid]
    __shared__ unsigned red_cnt[4][NBINS];   // 256 B: per-wave counts
    const int t = threadIdx.x;
    const int lane = t & 63;

    #pragma unroll
    for (int k = 0; k < NBINS; ++k) dsh[k * 256 + t] = 0.0f;
    __syncthreads();

    unsigned long long cLo = 0ULL, cHi = 0ULL;  // bins 0-7 / 8-15, 8b each

    const int T = gridDim.x * 256;
    for (int g0 = blockIdx.x * 256 + t; g0 < G; g0 += 2 * T) {
        const int g1 = g0 + T;
        const bool ok1 = (g1 < G);
        const int a0 = (g0 >> 16) * (3 * CH4) + (g0 & (CH4 - 1));
        const int a1 = ok1 ? (g1 >> 16) * (3 * CH4) + (g1 & (CH4 - 1)) : a0;

        // ---- phase A: input -> 8 bins (4-bit packed) + exclusion mask ----
        const f4 iA0 = __builtin_nontemporal_load(&input[a0]);
        const f4 iA1 = __builtin_nontemporal_load(&input[a0 + CH4]);
        const f4 iA2 = __builtin_nontemporal_load(&input[a0 + 2 * CH4]);
        const f4 iB0 = __builtin_nontemporal_load(&input[a1]);
        const f4 iB1 = __builtin_nontemporal_load(&input[a1 + CH4]);
        const f4 iB2 = __builtin_nontemporal_load(&input[a1 + 2 * CH4]);

        unsigned bpack = 0u, excl = ok1 ? 0u : 0xF0u;
        #pragma unroll
        for (int j = 0; j < 4; ++j) {
            const float ilA = luma_exact(iA0[j], iA1[j], iA2[j]);
            int bA = (int)floorf(__fmul_rn(ilA, 16.0f));
            bA = min(max(bA, 0), NBINS - 1);
            bpack |= (unsigned)bA << (4 * j);
            excl |= (ilA >= 1.0f ? 1u : 0u) << j;

            const float ilB = luma_exact(iB0[j], iB1[j], iB2[j]);
            int bB = (int)floorf(__fmul_rn(ilB, 16.0f));
            bB = min(max(bB, 0), NBINS - 1);
            bpack |= (unsigned)bB << (4 * (j + 4));
            excl |= (ilB >= 1.0f ? 1u : 0u) << (j + 4);
        }

        // ---- phase B: pred -> pl[8] ----
        const f4 pA0 = __builtin_nontemporal_load(&pred[a0]);
        const f4 pA1 = __builtin_nontemporal_load(&pred[a0 + CH4]);
        const f4 pA2 = __builtin_nontemporal_load(&pred[a0 + 2 * CH4]);
        const f4 pB0 = __builtin_nontemporal_load(&pred[a1]);
        const f4 pB1 = __builtin_nontemporal_load(&pred[a1 + CH4]);
        const f4 pB2 = __builtin_nontemporal_load(&pred[a1 + 2 * CH4]);
        float pl[8];
        #pragma unroll
        for (int j = 0; j < 4; ++j) {
            pl[j]     = luma_exact(pA0[j], pA1[j], pA2[j]);
            pl[j + 4] = luma_exact(pB0[j], pB1[j], pB2[j]);
        }

        // ---- phase C: target -> d, accumulate ----
        const f4 tA0 = __builtin_nontemporal_load(&target[a0]);
        const f4 tA1 = __builtin_nontemporal_load(&target[a0 + CH4]);
        const f4 tA2 = __builtin_nontemporal_load(&target[a0 + 2 * CH4]);
        const f4 tB0 = __builtin_nontemporal_load(&target[a1]);
        const f4 tB1 = __builtin_nontemporal_load(&target[a1 + CH4]);
        const f4 tB2 = __builtin_nontemporal_load(&target[a1 + 2 * CH4]);

        #pragma unroll
        for (int j = 0; j < 4; ++j) {
            {
                const float tlA = luma_exact(tA0[j], tA1[j], tA2[j]);
                if (!((excl >> j) & 1u)) {
                    const int b = (int)((bpack >> (4 * j)) & 0xFu);
                    dsh[b * 256 + t] += pl[j] - tlA;
                    const unsigned long long inc = 1ULL << ((b & 7) * 8);
                    if (b < 8) cLo += inc; else cHi += inc;
                }
            }
            {
                const float tlB = luma_exact(tB0[j], tB1[j], tB2[j]);
                if (!((excl >> (j + 4)) & 1u)) {
                    const int b = (int)((bpack >> (4 * (j + 4))) & 0xFu);
                    dsh[b * 256 + t] += pl[j + 4] - tlB;
                    const unsigned long long inc = 1ULL << ((b & 7) * 8);
                    if (b < 8) cLo += inc; else cHi += inc;
                }
            }
        }
    }

    // ---- counts: SWAR expand to 16b fields, wave shuffle-tree reduce ----
    // per-thread per-bin <= 8; 64-lane sum <= 512 -> fits 16b field.
    unsigned long long e0 = cLo & 0x00FF00FF00FF00FFULL;         // bins 0,2,4,6
    unsigned long long e1 = (cLo >> 8) & 0x00FF00FF00FF00FFULL;  // bins 1,3,5,7
    unsigned long long e2 = cHi & 0x00FF00FF00FF00FFULL;         // bins 8,10,12,14
    unsigned long long e3 = (cHi >> 8) & 0x00FF00FF00FF00FFULL;  // bins 9,11,13,15
    #pragma unroll
    for (int k = 32; k; k >>= 1) {
        e0 += __shfl_down(e0, k);
        e1 += __shfl_down(e1, k);
        e2 += __shfl_down(e2, k);
        e3 += __shfl_down(e3, k);
    }
    if (lane == 0) {
        const int w = t >> 6;
        #pragma unroll
        for (int f = 0; f < 4; ++f) {
            red_cnt[w][2 * f]         = (unsigned)((e0 >> (16 * f)) & 0xFFFFULL);
            red_cnt[w][2 * f + 1]     = (unsigned)((e1 >> (16 * f)) & 0xFFFFULL);
            red_cnt[w][8 + 2 * f]     = (unsigned)((e2 >> (16 * f)) & 0xFFFFULL);
            red_cnt[w][8 + 2 * f + 1] = (unsigned)((e3 >> (16 * f)) & 0xFFFFULL);
        }
    }
    __syncthreads();

    // ---- dsum epilogue: thread t reduces bin b=t>>4 over strip l=t&15 ----
    const int b = t >> 4, l = t & 15;
    float s = 0.0f;
    #pragma unroll
    for (int k = 0; k < 16; ++k) s += dsh[b * 256 + k * 16 + l];
    #pragma unroll
    for (int k = 8; k; k >>= 1) s += __shfl_down(s, k, 16);
    if (l == 0) {
        partials[b * rows + blockIdx.x] =
            (float)(red_cnt[0][b] + red_cnt[1][b] + red_cnt[2][b] + red_cnt[3][b]);
        partials[(NBINS + b) * rows + blockIdx.x] = s;
    }
}

__global__ __launch_bounds__(512) void tm_stage2(
    const float4* __restrict__ partials4,  // column-major [NCOL][rows/4]
    float* __restrict__ out, int rows4)
{
    __shared__ double col[NCOL];
    const int t = threadIdx.x;          // 512 = 32 cols x 16 threads
    const int c = t >> 4;
    const int l = t & 15;

    double s = 0.0;
    for (int k = l; k < rows4; k += 16) {
        const float4 v = partials4[c * rows4 + k];
        s += (double)v.x + (double)v.y + (double)v.z + (double)v.w;
    }
    #pragma unroll
    for (int k = 8; k; k >>= 1) s += __shfl_down(s, k, 16);
    if (l == 0) col[c] = s;
    __syncthreads();

    if (t == 0) {
        double acc = 0.0;
        #pragma unroll
        for (int i = 0; i < NBINS; ++i) {
            const double cnt = col[i];
            if (cnt > 0.0) acc += fabs(col[NBINS + i]) / cnt;
        }
        out[0] = (float)(acc / (double)NBINS);
    }
}

extern "C" void kernel_launch(void* const* d_in, const int* in_sizes, int n_in,
                              void* d_out, int out_size, void* d_ws, size_t ws_size,
                              hipStream_t stream) {
    const float* pred   = (const float*)d_in[0];
    const float* target = (const float*)d_in[1];
    const float* input  = (const float*)d_in[2];

    const int G = in_sizes[0] / 12;    // pixel float4-groups (1048576 here)

    int blocks = 2048;                 // 8 blocks/CU, all co-resident now
    const size_t maxRows = ws_size / (NCOL * sizeof(float));
    if ((size_t)blocks > maxRows) blocks = (int)maxRows;
    if (blocks < 1) blocks = 1;
    const int rows = (blocks + 3) & ~3;
    float* partials = (float*)d_ws;

    tm_stage1<<<blocks, 256, 0, stream>>>(
        (const f4*)pred, (const f4*)target, (const f4*)input,
        partials, G, rows);
    tm_stage2<<<1, 512, 0, stream>>>(
        (const float4*)partials, (float*)d_out, rows / 4);
}